// Round 2
// baseline (81.951 us; speedup 1.0000x reference)
//
#include <hip/hip_runtime.h>

#define GRID   64
#define BATCH  4
#define NV     512
#define NP     8192
#define NNET   2000
#define MAXPIN 8
#define NB     32          // nets per block (stage 1)
#define NCHUNK 63          // ceil(2000/32)
#define CELLS  (GRID * GRID)

__device__ __forceinline__ float sigmoidf_fast(float z) {
    return 1.0f / (1.0f + __expf(-z));
}

// Stage 1: each block (chunk, b) computes a 64x64 partial RUDY grid for its 32
// nets and stores it to a private d_ws slice. No atomics, no pre-zeroing.
__global__ __launch_bounds__(256)
void rudy_partial_kernel(const float* __restrict__ positions,
                         const float* __restrict__ pin_offsets,
                         const int*   __restrict__ net_to_pin,
                         const int*   __restrict__ pin_to_macro,
                         float* __restrict__ partial) {
    const int chunk = blockIdx.x;
    const int b     = blockIdx.y;
    const int t     = threadIdx.x;

    __shared__ float s_inx[NB][GRID];
    __shared__ float s_iny[NB][GRID];
    __shared__ float s_xmin[NB], s_xmax[NB], s_ymin[NB], s_ymax[NB], s_inv[NB];

    // ---- Phase A1: bbox per net, 8 lanes cooperate per net (shuffle reduce) ----
    {
        const int nl = t >> 3;      // local net 0..31
        const int j  = t & 7;       // pin slot
        const int n  = chunk * NB + nl;
        int pi = (n < NNET) ? net_to_pin[n * MAXPIN + j] : -1;
        int sp = pi > 0 ? pi : 0;
        int v  = pin_to_macro[sp];
        float px = positions[(b * NV + v) * 2 + 0] + pin_offsets[sp * 2 + 0];
        float py = positions[(b * NV + v) * 2 + 1] + pin_offsets[sp * 2 + 1];
        bool valid = pi >= 0;
        float xmx = valid ? px : -1e9f;
        float xmn = valid ? px :  1e9f;
        float ymx = valid ? py : -1e9f;
        float ymn = valid ? py :  1e9f;
        #pragma unroll
        for (int off = 1; off < 8; off <<= 1) {
            xmx = fmaxf(xmx, __shfl_xor(xmx, off, 64));
            xmn = fminf(xmn, __shfl_xor(xmn, off, 64));
            ymx = fmaxf(ymx, __shfl_xor(ymx, off, 64));
            ymn = fminf(ymn, __shfl_xor(ymn, off, 64));
        }
        if (j == 0) {
            float xming = (xmn + 1.0f) * 31.5f;   // (v+1)*0.5*(M-1)
            float xmaxg = (xmx + 1.0f) * 31.5f;
            float yming = (ymn + 1.0f) * 31.5f;
            float ymaxg = (ymx + 1.0f) * 31.5f;
            float size = fmaxf((xmaxg - xming + 1.0f) * (ymaxg - yming + 1.0f), 1.0f);
            s_xmin[nl] = xming; s_xmax[nl] = xmaxg;
            s_ymin[nl] = yming; s_ymax[nl] = ymaxg;
            s_inv[nl]  = 1.0f / size;
        }
    }
    __syncthreads();

    // ---- Phase A2: fill in_x / in_y (NB*128 = 4096 values, 16 per thread) ----
    #pragma unroll
    for (int i = 0; i < 16; ++i) {
        int v     = i * 256 + t;
        int n     = v >> 7;          // net
        int rem   = v & 127;
        int which = rem >> 6;        // 0 = x, 1 = y
        int coord = rem & 63;
        float c  = (float)coord;
        float lo = which ? s_ymin[n] : s_xmin[n];
        float hi = which ? s_ymax[n] : s_xmax[n];
        float val = sigmoidf_fast(2.0f * (c - lo + 0.5f)) *
                    sigmoidf_fast(2.0f * (hi - c + 0.5f));
        if (which) s_iny[n][coord] = val; else s_inx[n][coord] = val;
    }
    __syncthreads();

    // ---- Phase C: register-accumulate 16 cells/thread over all NB nets ----
    const int lane = t & 63;        // = x coordinate (2-way LDS alias: free)
    const int w    = t >> 6;        // wave id: owns rows y = w*16 .. w*16+15
    float acc[16];
    #pragma unroll
    for (int k = 0; k < 16; ++k) acc[k] = 0.0f;

    for (int n = 0; n < NB; ++n) {
        float xv = s_inx[n][lane] * s_inv[n];
        const float4* iny4 = (const float4*)&s_iny[n][w * 16];  // wave-uniform bcast
        #pragma unroll
        for (int k4 = 0; k4 < 4; ++k4) {
            float4 yv = iny4[k4];
            acc[k4 * 4 + 0] += yv.x * xv;
            acc[k4 * 4 + 1] += yv.y * xv;
            acc[k4 * 4 + 2] += yv.z * xv;
            acc[k4 * 4 + 3] += yv.w * xv;
        }
    }

    float* dst = partial + (b * NCHUNK + chunk) * CELLS;
    #pragma unroll
    for (int k = 0; k < 16; ++k) {
        dst[(w * 16 + k) * GRID + lane] = acc[k];   // plain coalesced store
    }
}

// Stage 2: one block per batch. Sum the 63 partials, separable 7x7 Gaussian,
// write rudy_smooth + penalty.
__global__ __launch_bounds__(1024)
void smooth_penalty_kernel(const float* __restrict__ partial,
                           float* __restrict__ out_penalty,
                           float* __restrict__ out_smooth) {
    const int b = blockIdx.x;
    const int t = threadIdx.x;

    __shared__ float tile[CELLS];
    __shared__ float tmp [CELLS];
    __shared__ float red[16];

    // 1D gaussian, sigma=1.5, ksize=7, normalized (separable == normalized 2D)
    float g[7];
    {
        float s = 0.0f;
        #pragma unroll
        for (int i = 0; i < 7; ++i) {
            float d = (float)(i - 3);
            g[i] = expf(-d * d / 4.5f);
            s += g[i];
        }
        float inv = 1.0f / s;
        #pragma unroll
        for (int i = 0; i < 7; ++i) g[i] *= inv;
    }

    // ---- reduce 63 partial grids: 4 cells/thread, chunk-major for ILP ----
    const float* base = partial + b * NCHUNK * CELLS;
    float sum[4] = {0.0f, 0.0f, 0.0f, 0.0f};
    for (int ch = 0; ch < NCHUNK; ++ch) {
        const float* p = base + ch * CELLS;
        #pragma unroll
        for (int k = 0; k < 4; ++k) sum[k] += p[k * 1024 + t];
    }
    #pragma unroll
    for (int k = 0; k < 4; ++k) tile[k * 1024 + t] = sum[k];
    __syncthreads();

    // ---- horizontal pass (zero padding) ----
    #pragma unroll
    for (int k = 0; k < 4; ++k) {
        int c = k * 1024 + t;
        int y = c >> 6, x = c & 63;
        float s = 0.0f;
        #pragma unroll
        for (int d = -3; d <= 3; ++d) {
            int xx = x + d;
            if (xx >= 0 && xx < GRID) s += g[d + 3] * tile[y * GRID + xx];
        }
        tmp[c] = s;
    }
    __syncthreads();

    // ---- vertical pass + outputs + penalty ----
    float local = 0.0f;
    #pragma unroll
    for (int k = 0; k < 4; ++k) {
        int c = k * 1024 + t;
        int y = c >> 6, x = c & 63;
        float s = 0.0f;
        #pragma unroll
        for (int d = -3; d <= 3; ++d) {
            int yy = y + d;
            if (yy >= 0 && yy < GRID) s += g[d + 3] * tmp[yy * GRID + x];
        }
        out_smooth[b * CELLS + c] = s;
        float ov = s - 1.0f;
        ov = ov > 0.0f ? ov : 0.0f;
        local += ov * ov;
    }

    // ---- block reduce (16 waves) ----
    #pragma unroll
    for (int off = 32; off > 0; off >>= 1) local += __shfl_down(local, off, 64);
    if ((t & 63) == 0) red[t >> 6] = local;
    __syncthreads();
    if (t == 0) {
        float s = 0.0f;
        #pragma unroll
        for (int i = 0; i < 16; ++i) s += red[i];
        out_penalty[b] = s;
    }
}

extern "C" void kernel_launch(void* const* d_in, const int* in_sizes, int n_in,
                              void* d_out, int out_size, void* d_ws, size_t ws_size,
                              hipStream_t stream) {
    const float* positions    = (const float*)d_in[0];
    const float* pin_offsets  = (const float*)d_in[1];
    const int*   net_to_pin   = (const int*)d_in[2];
    const int*   pin_to_macro = (const int*)d_in[3];
    float* out     = (float*)d_out;              // [0..3] penalty, [4..] rudy_smooth
    float* partial = (float*)d_ws;               // [B][NCHUNK][64*64] f32 partials

    rudy_partial_kernel<<<dim3(NCHUNK, BATCH), 256, 0, stream>>>(
        positions, pin_offsets, net_to_pin, pin_to_macro, partial);
    smooth_penalty_kernel<<<BATCH, 1024, 0, stream>>>(partial, out, out + BATCH);
}

// Round 3
// 80.944 us; speedup vs baseline: 1.0124x; 1.0124x over previous
//
#include <hip/hip_runtime.h>

#define GRID   64
#define BATCH  4
#define NV     512
#define NP     8192
#define NNET   2000
#define MAXPIN 8
#define NB     125         // nets per block (stage 1); 16*125 = 2000 exactly
#define NCHUNK 16
#define CELLS  (GRID * GRID)

__device__ __forceinline__ float sigmoidf_fast(float z) {
    return 1.0f / (1.0f + __expf(-z));
}

// Stage 1: each block (chunk, b) computes a 64x64 partial RUDY grid for its
// 125 nets and stores it to a private d_ws slice. No atomics, no pre-zeroing.
__global__ __launch_bounds__(256)
void rudy_partial_kernel(const float* __restrict__ positions,
                         const float* __restrict__ pin_offsets,
                         const int*   __restrict__ net_to_pin,
                         const int*   __restrict__ pin_to_macro,
                         float* __restrict__ partial) {
    const int chunk = blockIdx.x;
    const int b     = blockIdx.y;
    const int t     = threadIdx.x;

    __shared__ float s_inx[NB][GRID];
    __shared__ float s_iny[NB][GRID];
    __shared__ float s_xmin[NB], s_xmax[NB], s_ymin[NB], s_ymax[NB], s_inv[NB];

    // ---- Phase A1: bbox — one thread per net, int4-vectorized pin loads ----
    if (t < NB) {
        const int n = chunk * NB + t;
        const int4* np4 = (const int4*)(net_to_pin + n * MAXPIN);  // 32B aligned
        int4 q0 = np4[0], q1 = np4[1];
        int pis[8] = {q0.x, q0.y, q0.z, q0.w, q1.x, q1.y, q1.z, q1.w};
        float xmn = 1e9f, xmx = -1e9f, ymn = 1e9f, ymx = -1e9f;
        const float2* pos2 = (const float2*)positions;
        const float2* off2 = (const float2*)pin_offsets;
        #pragma unroll
        for (int j = 0; j < MAXPIN; ++j) {
            int pi = pis[j];
            int sp = pi > 0 ? pi : 0;
            int v  = pin_to_macro[sp];
            float2 p = pos2[b * NV + v];
            float2 o = off2[sp];
            float px = p.x + o.x, py = p.y + o.y;
            bool valid = pi >= 0;
            float vx_hi = valid ? px : -1e9f, vx_lo = valid ? px : 1e9f;
            float vy_hi = valid ? py : -1e9f, vy_lo = valid ? py : 1e9f;
            xmx = fmaxf(xmx, vx_hi); xmn = fminf(xmn, vx_lo);
            ymx = fmaxf(ymx, vy_hi); ymn = fminf(ymn, vy_lo);
        }
        float xming = (xmn + 1.0f) * 31.5f;   // (v+1)*0.5*(M-1)
        float xmaxg = (xmx + 1.0f) * 31.5f;
        float yming = (ymn + 1.0f) * 31.5f;
        float ymaxg = (ymx + 1.0f) * 31.5f;
        float size = fmaxf((xmaxg - xming + 1.0f) * (ymaxg - yming + 1.0f), 1.0f);
        s_xmin[t] = xming; s_xmax[t] = xmaxg;
        s_ymin[t] = yming; s_ymax[t] = ymaxg;
        s_inv[t]  = 1.0f / size;
    }
    __syncthreads();

    // ---- Phase A2: fill in_x / in_y (NB*128 = 16000 values) ----
    #pragma unroll
    for (int i = 0; i < 63; ++i) {              // 63*256 = 16128 >= 16000
        int v = i * 256 + t;
        if (v < NB * 128) {
            int n     = v >> 7;          // net
            int rem   = v & 127;
            int which = rem >> 6;        // 0 = x, 1 = y
            int coord = rem & 63;
            float c  = (float)coord;
            float lo = which ? s_ymin[n] : s_xmin[n];
            float hi = which ? s_ymax[n] : s_xmax[n];
            float val = sigmoidf_fast(2.0f * (c - lo + 0.5f)) *
                        sigmoidf_fast(2.0f * (hi - c + 0.5f));
            if (which) s_iny[n][coord] = val; else s_inx[n][coord] = val;
        }
    }
    __syncthreads();

    // ---- Phase C: register-accumulate 16 cells/thread over all NB nets ----
    const int lane = t & 63;        // = x coordinate (2-way LDS alias: free)
    const int w    = t >> 6;        // wave id: owns rows y = w*16 .. w*16+15
    float acc[16];
    #pragma unroll
    for (int k = 0; k < 16; ++k) acc[k] = 0.0f;

    #pragma unroll 5
    for (int n = 0; n < NB; ++n) {
        float xv = s_inx[n][lane] * s_inv[n];
        const float4* iny4 = (const float4*)&s_iny[n][w * 16];  // wave-uniform bcast
        #pragma unroll
        for (int k4 = 0; k4 < 4; ++k4) {
            float4 yv = iny4[k4];
            acc[k4 * 4 + 0] += yv.x * xv;
            acc[k4 * 4 + 1] += yv.y * xv;
            acc[k4 * 4 + 2] += yv.z * xv;
            acc[k4 * 4 + 3] += yv.w * xv;
        }
    }

    float* dst = partial + (b * NCHUNK + chunk) * CELLS;
    #pragma unroll
    for (int k = 0; k < 16; ++k) {
        dst[(w * 16 + k) * GRID + lane] = acc[k];   // plain coalesced store
    }
}

// Stage 2: one block per batch. Sum the 16 partials (float4, all loads in
// flight), separable 7x7 Gaussian, write rudy_smooth + penalty.
__global__ __launch_bounds__(1024)
void smooth_penalty_kernel(const float* __restrict__ partial,
                           float* __restrict__ out_penalty,
                           float* __restrict__ out_smooth) {
    const int b = blockIdx.x;
    const int t = threadIdx.x;

    __shared__ float tile[CELLS];
    __shared__ float tmp [CELLS];
    __shared__ float red[16];

    // 1D gaussian, sigma=1.5, ksize=7, normalized (separable == normalized 2D)
    float g[7];
    {
        float s = 0.0f;
        #pragma unroll
        for (int i = 0; i < 7; ++i) {
            float d = (float)(i - 3);
            g[i] = expf(-d * d / 4.5f);
            s += g[i];
        }
        float inv = 1.0f / s;
        #pragma unroll
        for (int i = 0; i < 7; ++i) g[i] *= inv;
    }

    // ---- reduce NCHUNK partial grids: one float4 (4 cells) per thread ----
    const float4* base4 = (const float4*)(partial + b * NCHUNK * CELLS);
    float4 s4 = make_float4(0.0f, 0.0f, 0.0f, 0.0f);
    #pragma unroll
    for (int ch = 0; ch < NCHUNK; ++ch) {       // fully unrolled: 16 loads in flight
        float4 v = base4[ch * 1024 + t];
        s4.x += v.x; s4.y += v.y; s4.z += v.z; s4.w += v.w;
    }
    ((float4*)tile)[t] = s4;
    __syncthreads();

    // ---- horizontal pass (zero padding) ----
    #pragma unroll
    for (int k = 0; k < 4; ++k) {
        int c = k * 1024 + t;
        int y = c >> 6, x = c & 63;
        float s = 0.0f;
        #pragma unroll
        for (int d = -3; d <= 3; ++d) {
            int xx = x + d;
            if (xx >= 0 && xx < GRID) s += g[d + 3] * tile[y * GRID + xx];
        }
        tmp[c] = s;
    }
    __syncthreads();

    // ---- vertical pass + outputs + penalty ----
    float local = 0.0f;
    #pragma unroll
    for (int k = 0; k < 4; ++k) {
        int c = k * 1024 + t;
        int y = c >> 6, x = c & 63;
        float s = 0.0f;
        #pragma unroll
        for (int d = -3; d <= 3; ++d) {
            int yy = y + d;
            if (yy >= 0 && yy < GRID) s += g[d + 3] * tmp[yy * GRID + x];
        }
        out_smooth[b * CELLS + c] = s;
        float ov = s - 1.0f;
        ov = ov > 0.0f ? ov : 0.0f;
        local += ov * ov;
    }

    // ---- block reduce (16 waves) ----
    #pragma unroll
    for (int off = 32; off > 0; off >>= 1) local += __shfl_down(local, off, 64);
    if ((t & 63) == 0) red[t >> 6] = local;
    __syncthreads();
    if (t == 0) {
        float s = 0.0f;
        #pragma unroll
        for (int i = 0; i < 16; ++i) s += red[i];
        out_penalty[b] = s;
    }
}

extern "C" void kernel_launch(void* const* d_in, const int* in_sizes, int n_in,
                              void* d_out, int out_size, void* d_ws, size_t ws_size,
                              hipStream_t stream) {
    const float* positions    = (const float*)d_in[0];
    const float* pin_offsets  = (const float*)d_in[1];
    const int*   net_to_pin   = (const int*)d_in[2];
    const int*   pin_to_macro = (const int*)d_in[3];
    float* out     = (float*)d_out;              // [0..3] penalty, [4..] rudy_smooth
    float* partial = (float*)d_ws;               // [B][NCHUNK][64*64] f32 partials

    rudy_partial_kernel<<<dim3(NCHUNK, BATCH), 256, 0, stream>>>(
        positions, pin_offsets, net_to_pin, pin_to_macro, partial);
    smooth_penalty_kernel<<<BATCH, 1024, 0, stream>>>(partial, out, out + BATCH);
}